// Round 4
// baseline (605.787 us; speedup 1.0000x reference)
//
#include <hip/hip_runtime.h>
#include <math.h>
#include <stdint.h>

// sigmoid-form heaviside: (tanh(5x)+1)/2 == 1/(1+exp(-10x)) (math identity)
__device__ __forceinline__ float hv(float x) {
    return __builtin_amdgcn_rcpf(1.0f + __expf(-10.0f * x));
}

// async global->LDS copies (vmcnt-tracked; LDS dest = wave-uniform base + lane*size)
__device__ __forceinline__ void gload16(const void* g, void* l) {
    __builtin_amdgcn_global_load_lds(
        (const __attribute__((address_space(1))) uint32_t*)g,
        (__attribute__((address_space(3))) uint32_t*)l, 16, 0, 0);
}
__device__ __forceinline__ void gload4(const void* g, void* l) {
    __builtin_amdgcn_global_load_lds(
        (const __attribute__((address_space(1))) uint32_t*)g,
        (__attribute__((address_space(3))) uint32_t*)l, 4, 0, 0);
}

// ---- kernel 1: per-basin MLP -> transformed params (8 planes of B) ----
__global__ void params_kernel(const float* __restrict__ attrs,
                              const float* __restrict__ w1,
                              const float* __restrict__ b1,
                              const float* __restrict__ w2,
                              const float* __restrict__ b2,
                              float* __restrict__ params, int B) {
    int b = blockIdx.x * blockDim.x + threadIdx.x;
    if (b >= B) return;
    float a[27];
#pragma unroll
    for (int i = 0; i < 27; ++i) a[i] = attrs[b * 27 + i];
    float h[32];
#pragma unroll
    for (int j = 0; j < 32; ++j) {
        float s = b1[j];
#pragma unroll
        for (int i = 0; i < 27; ++i) s = fmaf(a[i], w1[i * 32 + j], s);
        h[j] = tanhf(s);
    }
    float p[6];
#pragma unroll
    for (int k = 0; k < 6; ++k) {
        float s = b2[k];
#pragma unroll
        for (int j = 0; j < 32; ++j) s = fmaf(h[j], w2[j * 6 + k], s);
        p[k] = tanhf(s);
    }
    float tmin = (p[0] + 1.0f) * -1.5f;
    float tmax = (p[1] + 1.0f) * 1.5f;
    float ddf  = (p[2] + 1.0f) * 2.5f;
    float f    = (p[3] + 1.0f) / 20.0f;
    float smax = (p[4] + 1.0f) * 700.0f + 100.0f;
    float qmax = (p[5] + 1.0f) * 20.0f + 10.0f;
    params[0 * B + b] = tmin;
    params[1 * B + b] = tmax;
    params[2 * B + b] = ddf;
    params[3 * B + b] = f;
    params[4 * B + b] = smax;
    params[5 * B + b] = qmax;
    params[6 * B + b] = 1.0f / smax;
    params[7 * B + b] = f * 1.4426950408889634f;   // f*log2(e) for exp2-form
}

// ---- kernel 2: transpose + precompute per-(b,t) state-independent values. ----
__global__ __launch_bounds__(256)
void prep_kernel(const float* __restrict__ forcing,
                 const float* __restrict__ params,
                 float4* __restrict__ qv,
                 float* __restrict__ petT,
                 int B, int T) {
    __shared__ float raw[64][165];   // 160 floats/row + pad (stride 165: gcd(165,32)=1)
    int b0 = blockIdx.x * 64, t0 = blockIdx.y * 32;
    size_t total4 = ((size_t)B * T * 5) >> 2;
    for (int idx = threadIdx.x; idx < 64 * 40; idx += 256) {
        int row = idx / 40, quad = idx - row * 40;
        size_t f4 = ((((size_t)(b0 + row) * T + t0) * 5) >> 2) + quad;
        float4 v = make_float4(0.f, 0.f, 0.f, 0.f);
        if (f4 < total4) v = ((const float4*)forcing)[f4];
        raw[row][quad * 4 + 0] = v.x;
        raw[row][quad * 4 + 1] = v.y;
        raw[row][quad * 4 + 2] = v.z;
        raw[row][quad * 4 + 3] = v.w;
    }
    __syncthreads();
    int bl = threadIdx.x & 63;
    int b = b0 + bl;
    float tmin = params[0 * B + b], tmax = params[1 * B + b], ddf = params[2 * B + b];
    for (int tt = threadIdx.x >> 6; tt < 32; tt += 4) {
        int t = t0 + tt;
        if (t >= T) break;
        float p  = raw[bl][tt * 5 + 0];
        float tm = raw[bl][tt * 5 + 1];
        float dl = raw[bl][tt * 5 + 2];
        float pet = 29.8f * (dl * 24.0f) * 0.611f
                    * __expf(17.3f * tm / (tm + 237.3f)) / (tm + 273.2f);
        float psnow = hv(tmin - tm) * p;
        float prain = p - psnow;          // sigma(x)+sigma(-x)=1
        float dt2 = tm - tmax;
        float Hm1 = hv(dt2);
        float M = Hm1 * (ddf * dt2);      // melt = H(s0)*min(Hm1*s0, M)
        qv[(size_t)t * B + b] = make_float4(psnow, prain, Hm1, M);
        petT[(size_t)t * B + b] = pet;
    }
}

// ---- kernel 3: serial scan, LDS double-buffered 16-step chunks, fused output.
//      1 wave per block -> no barriers; ordering via counted s_waitcnt+sched_barrier.
//      Merged-reciprocal sigmoid pair with OVERFLOW-CLAMPED exp2 args:
//      hs1=1/P, over=1/Q, P=1+e1, Q=1+e2, e_i=2^min(C10*x,63)  (so P*Q<=2^126 finite)
//      loss = hs1*(over*A + (1-over)*Bv) == r*(A + e2*Bv),  r=rcp(P*Q)
//      qq   = hs1*(over*(qmax+d) + (1-over)*qex) == r*((qmax+d) + e2*qex)
//      Clamp perturbs only terms < 1e-16 (true sigmoid < 1e-19 there). s0>=0 always.
__global__ __launch_bounds__(64, 1)
void scan_kernel(const float4* __restrict__ qv,
                 const float* __restrict__ petT,
                 const float* __restrict__ params,
                 float* __restrict__ out,
                 int B, int T) {
    __shared__ float4 ldsQ[2][16][64];   // 32 KB
    __shared__ float  ldsP[2][16][64];   // 8 KB
    int lane = threadIdx.x;
    int b = blockIdx.x * 64 + lane;
    if (b >= B) return;
    const float smax = params[4 * B + b];
    const float qmax = params[5 * B + b];
    const float ism  = params[6 * B + b];
    const float fl2  = params[7 * B + b];
    const float C10  = -14.426950408889634f;   // -10*log2(e)
    const size_t bT = (size_t)b * T;
    float s0 = 0.0f, s1 = 0.0f;
    float obuf[16];
    float qq_last = 0.0f;

    auto flush16 = [&](int start) {   // write obuf[0..15] -> out[bT+start .. +15]
        if (((bT + (size_t)start) & 3) == 0) {
            float4* dst = (float4*)(out + bT + start);
            dst[0] = make_float4(obuf[0],  obuf[1],  obuf[2],  obuf[3]);
            dst[1] = make_float4(obuf[4],  obuf[5],  obuf[6],  obuf[7]);
            dst[2] = make_float4(obuf[8],  obuf[9],  obuf[10], obuf[11]);
            dst[3] = make_float4(obuf[12], obuf[13], obuf[14], obuf[15]);
        } else {
#pragma unroll
            for (int i = 0; i < 16; ++i) out[bT + start + i] = obuf[i];
        }
    };

    // one step; qq_last = output value for index (t-1) (state after step t-1)
#define STEP_MATH(q, pt)                                                  \
    {                                                                     \
        float e0   = exp2f(C10 * s0);                                     \
        float Hs0  = __builtin_amdgcn_rcpf(1.0f + e0);                    \
        float melt = Hs0 * fminf((q).z * s0, (q).w);                      \
        float d    = s1 - smax;                                           \
        float a1   = fminf(C10 * s1, 63.0f);                              \
        float a2   = fminf(C10 * d, 63.0f);                               \
        float e1   = exp2f(a1);                                           \
        float e2   = exp2f(a2);                                           \
        float r    = __builtin_amdgcn_rcpf((1.0f + e1) * (1.0f + e2));    \
        float ex   = exp2f(fl2 * d);                                      \
        float qex  = qmax * ex;                                           \
        float qd   = qmax + d;                                            \
        float A    = (pt) + qd;                                           \
        float Bv   = fmaf((pt) * ism, s1, qex);                           \
        float loss = r * fmaf(e2, Bv, A);                                 \
        qq_last    = r * fmaf(e2, qex, qd);                               \
        float ds0  = (q).x - melt;                                        \
        float ds1  = ((q).y + melt) - loss;                               \
        s0 += __builtin_amdgcn_fmed3f(ds0, -100000.0f, 100000.0f);        \
        s1 += __builtin_amdgcn_fmed3f(ds1, -100000.0f, 100000.0f);        \
    }

    int nFull = T / 16;
    int cur = 0;
    if (nFull > 0) {
        // prologue: stage chunk 0 into buf 0
        {
            const float4* qs = qv + b;
            const float*  ps = petT + b;
#pragma unroll
            for (int j = 0; j < 16; ++j) {
                gload16(qs + (size_t)j * B, &ldsQ[0][j][0]);
                gload4 (ps + (size_t)j * B, &ldsP[0][j][0]);
            }
        }
        asm volatile("s_waitcnt vmcnt(0)" ::: "memory");
        __builtin_amdgcn_sched_barrier(0);

        for (int c = 0; c < nFull - 1; ++c) {
            // stage chunk c+1 into the other buffer
            {
                const float4* qs = qv + ((size_t)(c + 1) * 16) * B + b;
                const float*  ps = petT + ((size_t)(c + 1) * 16) * B + b;
                int nxt = cur ^ 1;
#pragma unroll
                for (int j = 0; j < 16; ++j) {
                    gload16(qs + (size_t)j * B, &ldsQ[nxt][j][0]);
                    gload4 (ps + (size_t)j * B, &ldsP[nxt][j][0]);
                }
            }
            __builtin_amdgcn_sched_barrier(0);
            // compute chunk c from LDS buf cur (loads for c+1 in flight underneath)
            int t0 = 16 * c;
            bool doflush = (c > 0);
#pragma unroll
            for (int j = 0; j < 16; ++j) {
                float4 q = ldsQ[cur][j][lane];
                float pt = ldsP[cur][j][lane];
                STEP_MATH(q, pt);
                if (j == 0) {
                    if (doflush) { obuf[15] = qq_last; flush16(t0 - 16); }
                } else {
                    obuf[j - 1] = qq_last;
                }
            }
            asm volatile("s_waitcnt vmcnt(0)" ::: "memory");
            __builtin_amdgcn_sched_barrier(0);
            cur ^= 1;
        }
        // final chunk (no prefetch)
        {
            int t0 = 16 * (nFull - 1);
            bool doflush = (nFull > 1);
#pragma unroll
            for (int j = 0; j < 16; ++j) {
                float4 q = ldsQ[cur][j][lane];
                float pt = ldsP[cur][j][lane];
                STEP_MATH(q, pt);
                if (j == 0) {
                    if (doflush) { obuf[15] = qq_last; flush16(t0 - 16); }
                } else {
                    obuf[j - 1] = qq_last;
                }
            }
        }
    }
    // tail (T % 16 != 0): direct global loads + direct scalar output writes
    for (int t = nFull * 16; t < T; ++t) {
        float4 q = qv[(size_t)t * B + b];
        float pt = petT[(size_t)t * B + b];
        STEP_MATH(q, pt);
        if ((t & 15) == 0) {
            if (t > 0) { obuf[15] = qq_last; flush16(t - 16); }
        } else {
            out[bT + (t - 1)] = qq_last;
        }
    }
    // epilogue: output for t = T-1 from the final state (same clamped algebra)
    {
        float d   = s1 - smax;
        float a1  = fminf(C10 * s1, 63.0f);
        float a2  = fminf(C10 * d, 63.0f);
        float e1  = exp2f(a1);
        float e2  = exp2f(a2);
        float r   = __builtin_amdgcn_rcpf((1.0f + e1) * (1.0f + e2));
        float ex  = exp2f(fl2 * d);
        float qex = qmax * ex;
        float qd  = qmax + d;
        float qqf = r * fmaf(e2, qex, qd);
        if ((T & 15) == 0) {
            if (T > 0) { obuf[15] = qqf; flush16(T - 16); }
        } else {
            out[bT + (T - 1)] = qqf;
        }
    }
#undef STEP_MATH
}

extern "C" void kernel_launch(void* const* d_in, const int* in_sizes, int n_in,
                              void* d_out, int out_size, void* d_ws, size_t ws_size,
                              hipStream_t stream) {
    const float* forcing = (const float*)d_in[0];
    const float* attrs   = (const float*)d_in[1];
    const float* w1      = (const float*)d_in[2];
    const float* b1      = (const float*)d_in[3];
    const float* w2      = (const float*)d_in[4];
    const float* b2      = (const float*)d_in[5];
    float* out = (float*)d_out;

    int B = in_sizes[1] / 27;
    int T = in_sizes[0] / (B * 5);

    char* ws = (char*)d_ws;
    size_t off = 0;
    float4* qv   = (float4*)(ws + off); off += (size_t)B * T * sizeof(float4);
    float* petT  = (float*)(ws + off);  off += (size_t)B * T * sizeof(float);
    float* params = (float*)(ws + off); off += (size_t)8 * B * sizeof(float);

    params_kernel<<<(B + 255) / 256, 256, 0, stream>>>(attrs, w1, b1, w2, b2, params, B);
    dim3 g2(B / 64, (T + 31) / 32);
    prep_kernel<<<g2, 256, 0, stream>>>(forcing, params, qv, petT, B, T);
    scan_kernel<<<(B + 63) / 64, 64, 0, stream>>>(qv, petT, params, out, B, T);
}

// Round 5
// 596.741 us; speedup vs baseline: 1.0152x; 1.0152x over previous
//
#include <hip/hip_runtime.h>
#include <math.h>
#include <stdint.h>

// sigmoid-form heaviside: (tanh(5x)+1)/2 == 1/(1+exp(-10x)) (math identity)
__device__ __forceinline__ float hv(float x) {
    return __builtin_amdgcn_rcpf(1.0f + __expf(-10.0f * x));
}

// async global->LDS copies (vmcnt-tracked; LDS dest = wave-uniform base + lane*size)
__device__ __forceinline__ void gload16(const void* g, void* l) {
    __builtin_amdgcn_global_load_lds(
        (const __attribute__((address_space(1))) uint32_t*)g,
        (__attribute__((address_space(3))) uint32_t*)l, 16, 0, 0);
}
__device__ __forceinline__ void gload4(const void* g, void* l) {
    __builtin_amdgcn_global_load_lds(
        (const __attribute__((address_space(1))) uint32_t*)g,
        (__attribute__((address_space(3))) uint32_t*)l, 4, 0, 0);
}

// ---- kernel 1: per-basin MLP -> transformed params (8 planes of B) ----
__global__ void params_kernel(const float* __restrict__ attrs,
                              const float* __restrict__ w1,
                              const float* __restrict__ b1,
                              const float* __restrict__ w2,
                              const float* __restrict__ b2,
                              float* __restrict__ params, int B) {
    int b = blockIdx.x * blockDim.x + threadIdx.x;
    if (b >= B) return;
    float a[27];
#pragma unroll
    for (int i = 0; i < 27; ++i) a[i] = attrs[b * 27 + i];
    float h[32];
#pragma unroll
    for (int j = 0; j < 32; ++j) {
        float s = b1[j];
#pragma unroll
        for (int i = 0; i < 27; ++i) s = fmaf(a[i], w1[i * 32 + j], s);
        h[j] = tanhf(s);
    }
    float p[6];
#pragma unroll
    for (int k = 0; k < 6; ++k) {
        float s = b2[k];
#pragma unroll
        for (int j = 0; j < 32; ++j) s = fmaf(h[j], w2[j * 6 + k], s);
        p[k] = tanhf(s);
    }
    float tmin = (p[0] + 1.0f) * -1.5f;
    float tmax = (p[1] + 1.0f) * 1.5f;
    float ddf  = (p[2] + 1.0f) * 2.5f;
    float f    = (p[3] + 1.0f) / 20.0f;
    float smax = (p[4] + 1.0f) * 700.0f + 100.0f;
    float qmax = (p[5] + 1.0f) * 20.0f + 10.0f;
    params[0 * B + b] = tmin;
    params[1 * B + b] = tmax;
    params[2 * B + b] = ddf;
    params[3 * B + b] = f;
    params[4 * B + b] = smax;
    params[5 * B + b] = qmax;
    params[6 * B + b] = 1.0f / smax;
    params[7 * B + b] = f * 1.4426950408889634f;   // f*log2(e) for exp2-form
}

// ---- kernel 2: transpose + precompute per-(b,t) state-independent values. ----
__global__ __launch_bounds__(256)
void prep_kernel(const float* __restrict__ forcing,
                 const float* __restrict__ params,
                 float4* __restrict__ qv,
                 float* __restrict__ petT,
                 int B, int T) {
    __shared__ float raw[64][165];   // 160 floats/row + pad (stride 165: gcd(165,32)=1)
    int b0 = blockIdx.x * 64, t0 = blockIdx.y * 32;
    size_t total4 = ((size_t)B * T * 5) >> 2;
    for (int idx = threadIdx.x; idx < 64 * 40; idx += 256) {
        int row = idx / 40, quad = idx - row * 40;
        size_t f4 = ((((size_t)(b0 + row) * T + t0) * 5) >> 2) + quad;
        float4 v = make_float4(0.f, 0.f, 0.f, 0.f);
        if (f4 < total4) v = ((const float4*)forcing)[f4];
        raw[row][quad * 4 + 0] = v.x;
        raw[row][quad * 4 + 1] = v.y;
        raw[row][quad * 4 + 2] = v.z;
        raw[row][quad * 4 + 3] = v.w;
    }
    __syncthreads();
    int bl = threadIdx.x & 63;
    int b = b0 + bl;
    float tmin = params[0 * B + b], tmax = params[1 * B + b], ddf = params[2 * B + b];
    for (int tt = threadIdx.x >> 6; tt < 32; tt += 4) {
        int t = t0 + tt;
        if (t >= T) break;
        float p  = raw[bl][tt * 5 + 0];
        float tm = raw[bl][tt * 5 + 1];
        float dl = raw[bl][tt * 5 + 2];
        float pet = 29.8f * (dl * 24.0f) * 0.611f
                    * __expf(17.3f * tm / (tm + 237.3f)) / (tm + 273.2f);
        float psnow = hv(tmin - tm) * p;
        float prain = p - psnow;          // sigma(x)+sigma(-x)=1
        float dt2 = tm - tmax;
        float Hm1 = hv(dt2);
        float M = Hm1 * (ddf * dt2);      // melt = H(s0)*min(Hm1*s0, M)
        qv[(size_t)t * B + b] = make_float4(psnow, prain, Hm1, M);
        petT[(size_t)t * B + b] = pet;
    }
}

// ---- kernel 3: serial scan, LDS double-buffered 16-step chunks, fused output.
//      This round: LDS reads software-pipelined 2 steps ahead via explicit
//      register rotation (static unroll) so ds_read latency (~120cy) is hidden
//      under ~2 steps of math instead of being serially exposed per step.
__global__ __launch_bounds__(64, 1)
void scan_kernel(const float4* __restrict__ qv,
                 const float* __restrict__ petT,
                 const float* __restrict__ params,
                 float* __restrict__ out,
                 int B, int T) {
    __shared__ float4 ldsQ[2][16][64];   // 32 KB
    __shared__ float  ldsP[2][16][64];   // 8 KB
    int lane = threadIdx.x;
    int b = blockIdx.x * 64 + lane;
    if (b >= B) return;
    const float smax = params[4 * B + b];
    const float qmax = params[5 * B + b];
    const float ism  = params[6 * B + b];
    const float fl2  = params[7 * B + b];
    const float C10  = -14.426950408889634f;   // -10*log2(e)
    const size_t bT = (size_t)b * T;
    float s0 = 0.0f, s1 = 0.0f;
    float obuf[16];
    float qq_last = 0.0f;

    auto flush16 = [&](int start) {   // write obuf[0..15] -> out[bT+start .. +15]
        if (((bT + (size_t)start) & 3) == 0) {
            float4* dst = (float4*)(out + bT + start);
            dst[0] = make_float4(obuf[0],  obuf[1],  obuf[2],  obuf[3]);
            dst[1] = make_float4(obuf[4],  obuf[5],  obuf[6],  obuf[7]);
            dst[2] = make_float4(obuf[8],  obuf[9],  obuf[10], obuf[11]);
            dst[3] = make_float4(obuf[12], obuf[13], obuf[14], obuf[15]);
        } else {
#pragma unroll
            for (int i = 0; i < 16; ++i) out[bT + start + i] = obuf[i];
        }
    };

    // one step; qq_last = output value for index (t-1) (state after step t-1)
#define STEP_MATH(q, pt)                                                  \
    {                                                                     \
        float e0   = exp2f(C10 * s0);                                     \
        float Hs0  = __builtin_amdgcn_rcpf(1.0f + e0);                    \
        float melt = Hs0 * fminf((q).z * s0, (q).w);                      \
        float d    = s1 - smax;                                           \
        float a1   = fminf(C10 * s1, 63.0f);                              \
        float a2   = fminf(C10 * d, 63.0f);                               \
        float e1   = exp2f(a1);                                           \
        float e2   = exp2f(a2);                                           \
        float r    = __builtin_amdgcn_rcpf((1.0f + e1) * (1.0f + e2));    \
        float ex   = exp2f(fl2 * d);                                      \
        float qex  = qmax * ex;                                           \
        float qd   = qmax + d;                                            \
        float A    = (pt) + qd;                                           \
        float Bv   = fmaf((pt) * ism, s1, qex);                           \
        float loss = r * fmaf(e2, Bv, A);                                 \
        qq_last    = r * fmaf(e2, qex, qd);                               \
        float ds0  = (q).x - melt;                                        \
        float ds1  = ((q).y + melt) - loss;                               \
        s0 += __builtin_amdgcn_fmed3f(ds0, -100000.0f, 100000.0f);        \
        s1 += __builtin_amdgcn_fmed3f(ds1, -100000.0f, 100000.0f);        \
    }

    // compute one 16-step chunk from buf `cur` with 2-ahead pipelined LDS reads
#define CHUNK_BODY(t0base, doflush)                                       \
    {                                                                     \
        float4 q0 = ldsQ[cur][0][lane], q1 = ldsQ[cur][1][lane];          \
        float  p0 = ldsP[cur][0][lane], p1 = ldsP[cur][1][lane];          \
        _Pragma("unroll")                                                 \
        for (int j = 0; j < 16; ++j) {                                    \
            float4 qn; float pn;                                          \
            if (j < 14) { qn = ldsQ[cur][j + 2][lane];                    \
                          pn = ldsP[cur][j + 2][lane]; }                  \
            STEP_MATH(q0, p0);                                            \
            if (j == 0) {                                                 \
                if (doflush) { obuf[15] = qq_last; flush16((t0base) - 16); } \
            } else {                                                      \
                obuf[j - 1] = qq_last;                                    \
            }                                                             \
            q0 = q1; p0 = p1;                                             \
            if (j < 14) { q1 = qn; p1 = pn; }                             \
        }                                                                 \
    }

    int nFull = T / 16;
    int cur = 0;
    if (nFull > 0) {
        // prologue: stage chunk 0 into buf 0
        {
            const float4* qs = qv + b;
            const float*  ps = petT + b;
#pragma unroll
            for (int j = 0; j < 16; ++j) {
                gload16(qs + (size_t)j * B, &ldsQ[0][j][0]);
                gload4 (ps + (size_t)j * B, &ldsP[0][j][0]);
            }
        }
        asm volatile("s_waitcnt vmcnt(0)" ::: "memory");
        __builtin_amdgcn_sched_barrier(0);

        for (int c = 0; c < nFull - 1; ++c) {
            // stage chunk c+1 into the other buffer
            {
                const float4* qs = qv + ((size_t)(c + 1) * 16) * B + b;
                const float*  ps = petT + ((size_t)(c + 1) * 16) * B + b;
                int nxt = cur ^ 1;
#pragma unroll
                for (int j = 0; j < 16; ++j) {
                    gload16(qs + (size_t)j * B, &ldsQ[nxt][j][0]);
                    gload4 (ps + (size_t)j * B, &ldsP[nxt][j][0]);
                }
            }
            __builtin_amdgcn_sched_barrier(0);
            // compute chunk c from LDS buf cur (loads for c+1 in flight underneath)
            CHUNK_BODY(16 * c, (c > 0));
            asm volatile("s_waitcnt vmcnt(0)" ::: "memory");
            __builtin_amdgcn_sched_barrier(0);
            cur ^= 1;
        }
        // final chunk (no prefetch)
        CHUNK_BODY(16 * (nFull - 1), (nFull > 1));
    }
    // tail (T % 16 != 0): direct global loads + direct scalar output writes
    for (int t = nFull * 16; t < T; ++t) {
        float4 q = qv[(size_t)t * B + b];
        float pt = petT[(size_t)t * B + b];
        STEP_MATH(q, pt);
        if ((t & 15) == 0) {
            if (t > 0) { obuf[15] = qq_last; flush16(t - 16); }
        } else {
            out[bT + (t - 1)] = qq_last;
        }
    }
    // epilogue: output for t = T-1 from the final state (same clamped algebra)
    {
        float d   = s1 - smax;
        float a1  = fminf(C10 * s1, 63.0f);
        float a2  = fminf(C10 * d, 63.0f);
        float e1  = exp2f(a1);
        float e2  = exp2f(a2);
        float r   = __builtin_amdgcn_rcpf((1.0f + e1) * (1.0f + e2));
        float ex  = exp2f(fl2 * d);
        float qex = qmax * ex;
        float qd  = qmax + d;
        float qqf = r * fmaf(e2, qex, qd);
        if ((T & 15) == 0) {
            if (T > 0) { obuf[15] = qqf; flush16(T - 16); }
        } else {
            out[bT + (T - 1)] = qqf;
        }
    }
#undef CHUNK_BODY
#undef STEP_MATH
}

extern "C" void kernel_launch(void* const* d_in, const int* in_sizes, int n_in,
                              void* d_out, int out_size, void* d_ws, size_t ws_size,
                              hipStream_t stream) {
    const float* forcing = (const float*)d_in[0];
    const float* attrs   = (const float*)d_in[1];
    const float* w1      = (const float*)d_in[2];
    const float* b1      = (const float*)d_in[3];
    const float* w2      = (const float*)d_in[4];
    const float* b2      = (const float*)d_in[5];
    float* out = (float*)d_out;

    int B = in_sizes[1] / 27;
    int T = in_sizes[0] / (B * 5);

    char* ws = (char*)d_ws;
    size_t off = 0;
    float4* qv   = (float4*)(ws + off); off += (size_t)B * T * sizeof(float4);
    float* petT  = (float*)(ws + off);  off += (size_t)B * T * sizeof(float);
    float* params = (float*)(ws + off); off += (size_t)8 * B * sizeof(float);

    params_kernel<<<(B + 255) / 256, 256, 0, stream>>>(attrs, w1, b1, w2, b2, params, B);
    dim3 g2(B / 64, (T + 31) / 32);
    prep_kernel<<<g2, 256, 0, stream>>>(forcing, params, qv, petT, B, T);
    scan_kernel<<<(B + 63) / 64, 64, 0, stream>>>(qv, petT, params, out, B, T);
}